// Round 1
// baseline (102.571 us; speedup 1.0000x reference)
//
#include <hip/hip_runtime.h>

#define HD  16    // hidden_dim
#define DIM 256   // query dim
#define NW  65    // 4*HD+1 weights per box
#define HW  64    // grid H=W

// ---------------------------------------------------------------------------
// Kernel 1: W[n][j] = bg[j] + sum_d q[n][d] * Wg[d][j]
// Flat thread-per-output GEMM: 2400*65 = 156000 dots of depth 256.
// All lanes active (vs 65/256 in the old fused phase-1), float4 q loads,
// Wg loads coalesced across consecutive-j lanes. ~610 blocks -> fills chip.
// ---------------------------------------------------------------------------
__global__ __launch_bounds__(256, 8) void weights_kernel(
    const float* __restrict__ queries,  // (N,DIM)
    const float* __restrict__ Wg,       // (DIM,NW)
    const float* __restrict__ bg,       // (NW)
    float* __restrict__ W,              // (N,NW) workspace
    int total)                          // N*NW
{
    const int idx = blockIdx.x * 256 + threadIdx.x;
    if (idx >= total) return;
    const unsigned n = (unsigned)idx / NW;      // magic-mul div by const
    const int j = idx - (int)n * NW;

    const float4* q4  = reinterpret_cast<const float4*>(queries + (size_t)n * DIM);
    const float*  wgj = Wg + j;

    float a0 = 0.f, a1 = 0.f, a2 = 0.f, a3 = 0.f;   // 4-way ILP
    #pragma unroll 4
    for (int d4 = 0; d4 < DIM / 4; ++d4) {
        const float4 qv = q4[d4];
        const int d = d4 * 4;
        a0 = fmaf(qv.x, wgj[(d + 0) * NW], a0);
        a1 = fmaf(qv.y, wgj[(d + 1) * NW], a1);
        a2 = fmaf(qv.z, wgj[(d + 2) * NW], a2);
        a3 = fmaf(qv.w, wgj[(d + 3) * NW], a3);
    }
    W[idx] = bg[j] + ((a0 + a1) + (a2 + a3));
}

// force a block-uniform float into an SGPR
__device__ __forceinline__ float uload(const float* p) {
    return __int_as_float(__builtin_amdgcn_readfirstlane(__float_as_int(*p)));
}

// ---------------------------------------------------------------------------
// Kernel 2: pure render. One block per box. Weights come from global at a
// block-uniform address -> SGPRs (readfirstlane-pinned): no LDS, no barrier,
// ~50 VGPRs -> 8 blocks/CU resident. Inner loop identical numerics to the
// verified kernel (absmax was 0.25 with this accumulation order).
// ---------------------------------------------------------------------------
__global__ __launch_bounds__(256, 8) void render_kernel(
    const float* __restrict__ pos,      // (N,4)
    const float* __restrict__ W,        // (N,NW)
    float* __restrict__ out)            // (N,HW,HW)
{
    const int n   = blockIdx.x;
    const int tid = threadIdx.x;

    const float* wn = W + (size_t)n * NW;

    const float cx     = uload(pos + n * 4 + 0);
    const float cy     = uload(pos + n * 4 + 1);
    const float inv_bw = 1.0f / uload(pos + n * 4 + 2);
    const float inv_bh = 1.0f / uload(pos + n * 4 + 3);

    float w1x[HD], w1y[HD], b1[HD], w2[HD];
    #pragma unroll
    for (int k = 0; k < HD; ++k) {
        w1x[k] = uload(wn + k);
        w1y[k] = uload(wn + HD + k);
        b1[k]  = uload(wn + 2 * HD + k);
        w2[k]  = uload(wn + 3 * HD + k);
    }
    const float b2 = uload(wn + 4 * HD);

    const int xg = tid & 15;   // owns x0..x0+3
    const int yl = tid >> 4;   // 0..15
    const int x0 = xg * 4;

    float rx[4];
    #pragma unroll
    for (int j = 0; j < 4; ++j)
        rx[j] = ((x0 + j + 0.5f) * (1.0f / HW) - cx) * inv_bw;

    float* outn = out + (size_t)n * (HW * HW);

    #pragma unroll
    for (int it = 0; it < 4; ++it) {
        const int y = it * 16 + yl;
        const float ry = ((y + 0.5f) * (1.0f / HW) - cy) * inv_bh;

        float ayb[HD];
        #pragma unroll
        for (int k = 0; k < HD; ++k)
            ayb[k] = fmaf(ry, w1y[k], b1[k]);

        float4 acc = make_float4(b2, b2, b2, b2);
        #pragma unroll
        for (int k = 0; k < HD; ++k) {
            const float t0 = fmaxf(fmaf(rx[0], w1x[k], ayb[k]), 0.0f);
            const float t1 = fmaxf(fmaf(rx[1], w1x[k], ayb[k]), 0.0f);
            const float t2 = fmaxf(fmaf(rx[2], w1x[k], ayb[k]), 0.0f);
            const float t3 = fmaxf(fmaf(rx[3], w1x[k], ayb[k]), 0.0f);
            acc.x = fmaf(t0, w2[k], acc.x);
            acc.y = fmaf(t1, w2[k], acc.y);
            acc.z = fmaf(t2, w2[k], acc.z);
            acc.w = fmaf(t3, w2[k], acc.w);
        }
        *reinterpret_cast<float4*>(outn + y * HW + x0) = acc;
    }
}

extern "C" void kernel_launch(void* const* d_in, const int* in_sizes, int n_in,
                              void* d_out, int out_size, void* d_ws, size_t ws_size,
                              hipStream_t stream) {
    const float* pos = (const float*)d_in[0];
    const float* q   = (const float*)d_in[1];
    const float* Wg  = (const float*)d_in[2];
    const float* bg  = (const float*)d_in[3];
    float* out = (float*)d_out;

    const int N = in_sizes[0] / 4;       // 8*300 = 2400 boxes
    const int total = N * NW;            // 156000 weight dots
    float* W = (float*)d_ws;             // 624 KB of the 256 MB workspace

    weights_kernel<<<(total + 255) / 256, 256, 0, stream>>>(q, Wg, bg, W, total);
    render_kernel<<<N, 256, 0, stream>>>(pos, W, out);
}

// Round 2
// 92.177 us; speedup vs baseline: 1.1128x; 1.1128x over previous
//
#include <hip/hip_runtime.h>

#define HD  16    // hidden_dim
#define DIM 256   // query dim
#define NW  65    // 4*HD+1 weights per box
#define HW  64    // grid H=W

// One block per box n, 4 waves.
// Phase 1 (all 256 lanes): wave g computes partial dots over d in [64g,64g+64)
//   for all 65 columns (lane j -> column j; lanes 0..3 of wave 0 cover col 64).
//   Partials reduced via LDS. 4x shorter per-thread L2 load chain than the
//   old 65-thread serial version, and no idle waves at the barrier.
// Phase 2: identical to the verified 96.2us renderer: thread owns 4x4 pixels,
//   pre = rx*w1x[k] + (ry*w1y[k] + b1[k]); float4 stores, waves write 1KB rows.
// launch_bounds (256,4): ~100 live VGPRs fits the 128 cap -> NO spills
// (round-1 lesson: (256,8) forced a 64-VGPR cap and spilled in the hot loop).
__global__ __launch_bounds__(256, 4) void posmlp_kernel(
    const float* __restrict__ pos,      // (N,4)
    const float* __restrict__ queries,  // (N,DIM)
    const float* __restrict__ Wg,       // (DIM,NW)
    const float* __restrict__ bg,       // (NW)
    float* __restrict__ out)            // (N,HW,HW)
{
    const int n   = blockIdx.x;
    const int tid = threadIdx.x;

    __shared__ float qs[DIM];
    __shared__ float part[4][NW];
    __shared__ float wl[NW];

    qs[tid] = queries[n * DIM + tid];

    // uniform pos loads issued early so they overlap phase 1
    const float cx     = pos[n * 4 + 0];
    const float cy     = pos[n * 4 + 1];
    const float inv_bw = 1.0f / pos[n * 4 + 2];
    const float inv_bh = 1.0f / pos[n * 4 + 3];

    __syncthreads();

    // ---- phase 1: weights = q @ Wg + bg, 4-wave-parallel over d-chunks ----
    {
        const int j  = tid & 63;     // column
        const int g  = tid >> 6;     // wave = d-chunk
        const int db = g * 64;
        const float* wgj = Wg + j;
        float a0 = 0.f, a1 = 0.f, a2 = 0.f, a3 = 0.f;
        #pragma unroll 4
        for (int d = 0; d < 64; d += 4) {
            a0 = fmaf(qs[db + d + 0], wgj[(db + d + 0) * NW], a0);
            a1 = fmaf(qs[db + d + 1], wgj[(db + d + 1) * NW], a1);
            a2 = fmaf(qs[db + d + 2], wgj[(db + d + 2) * NW], a2);
            a3 = fmaf(qs[db + d + 3], wgj[(db + d + 3) * NW], a3);
        }
        part[g][j] = (a0 + a1) + (a2 + a3);

        if (tid < 4) {               // column 64 partials (wave 0 only)
            const int db4 = tid * 64;
            const float* wg64 = Wg + 64;
            float c0 = 0.f, c1 = 0.f, c2 = 0.f, c3 = 0.f;
            #pragma unroll 4
            for (int d = 0; d < 64; d += 4) {
                c0 = fmaf(qs[db4 + d + 0], wg64[(db4 + d + 0) * NW], c0);
                c1 = fmaf(qs[db4 + d + 1], wg64[(db4 + d + 1) * NW], c1);
                c2 = fmaf(qs[db4 + d + 2], wg64[(db4 + d + 2) * NW], c2);
                c3 = fmaf(qs[db4 + d + 3], wg64[(db4 + d + 3) * NW], c3);
            }
            part[tid][64] = (c0 + c1) + (c2 + c3);
        }
    }
    __syncthreads();

    if (tid < NW)
        wl[tid] = bg[tid] +
                  ((part[0][tid] + part[1][tid]) + (part[2][tid] + part[3][tid]));
    __syncthreads();

    // ---- phase 2: render ----
    float w1x[HD], w1y[HD], b1[HD], w2[HD];
    #pragma unroll
    for (int k = 0; k < HD; ++k) {
        w1x[k] = wl[k];
        w1y[k] = wl[HD + k];
        b1[k]  = wl[2 * HD + k];
        w2[k]  = wl[3 * HD + k];
    }
    const float b2 = wl[4 * HD];

    const int xg = tid & 15;   // x-group: owns x0..x0+3
    const int yl = tid >> 4;   // 0..15
    const int x0 = xg * 4;

    float rx[4];
    #pragma unroll
    for (int j = 0; j < 4; ++j)
        rx[j] = ((x0 + j + 0.5f) * (1.0f / HW) - cx) * inv_bw;

    float* outn = out + (size_t)n * (HW * HW);

    #pragma unroll
    for (int it = 0; it < 4; ++it) {
        const int y = it * 16 + yl;
        const float ry = ((y + 0.5f) * (1.0f / HW) - cy) * inv_bh;

        float ayb[HD];
        #pragma unroll
        for (int k = 0; k < HD; ++k)
            ayb[k] = fmaf(ry, w1y[k], b1[k]);

        float4 acc = make_float4(b2, b2, b2, b2);
        #pragma unroll
        for (int k = 0; k < HD; ++k) {
            const float t0 = fmaxf(fmaf(rx[0], w1x[k], ayb[k]), 0.0f);
            const float t1 = fmaxf(fmaf(rx[1], w1x[k], ayb[k]), 0.0f);
            const float t2 = fmaxf(fmaf(rx[2], w1x[k], ayb[k]), 0.0f);
            const float t3 = fmaxf(fmaf(rx[3], w1x[k], ayb[k]), 0.0f);
            acc.x = fmaf(t0, w2[k], acc.x);
            acc.y = fmaf(t1, w2[k], acc.y);
            acc.z = fmaf(t2, w2[k], acc.z);
            acc.w = fmaf(t3, w2[k], acc.w);
        }
        *reinterpret_cast<float4*>(outn + y * HW + x0) = acc;
    }
}

extern "C" void kernel_launch(void* const* d_in, const int* in_sizes, int n_in,
                              void* d_out, int out_size, void* d_ws, size_t ws_size,
                              hipStream_t stream) {
    const float* pos = (const float*)d_in[0];
    const float* q   = (const float*)d_in[1];
    const float* Wg  = (const float*)d_in[2];
    const float* bg  = (const float*)d_in[3];
    float* out = (float*)d_out;

    const int N = in_sizes[0] / 4;   // 8*300 = 2400 boxes
    posmlp_kernel<<<N, 256, 0, stream>>>(pos, q, Wg, bg, out);
}

// Round 3
// 90.486 us; speedup vs baseline: 1.1336x; 1.0187x over previous
//
#include <hip/hip_runtime.h>

#define HD  16    // hidden_dim
#define DIM 256   // query dim
#define NW  65    // 4*HD+1 weights per box
#define HW  64    // grid H=W
#define NB  2     // boxes per block (Wg reuse factor)

// One block per NB=2 boxes, 4 waves.
// Phase 1: wave g computes partial dots over d in [64g,64g+64) for all 65
//   columns x NB boxes. Each Wg load now feeds NB fmas -> L2 traffic for Wg
//   drops from 2400*64KB=154MB to 77MB. qs[b][d] is a wave-uniform LDS
//   broadcast (conflict-free). Lanes j of each wave own column j; col 64
//   covered by tid<8 (chunk=tid>>1, box=tid&1).
// Phase 2: the verified renderer, sequentially per box; registers reused
//   across the unrolled b-loop so liveness stays ~100 VGPR (no spill at the
//   (256,4) 128-VGPR cap -- round-1 lesson).
// Accumulation order per box is identical to the round-2 kernel (absmax 1.0,
// passed): 4-way stride-4 partials, (a0+a1)+(a2+a3), then 4-chunk reduce.
__global__ __launch_bounds__(256, 4) void posmlp_kernel(
    const float* __restrict__ pos,      // (N,4)
    const float* __restrict__ queries,  // (N,DIM)
    const float* __restrict__ Wg,       // (DIM,NW)
    const float* __restrict__ bg,       // (NW)
    float* __restrict__ out)            // (N,HW,HW)
{
    const int n0  = blockIdx.x * NB;
    const int tid = threadIdx.x;

    __shared__ float qs[NB][DIM];
    __shared__ float part[4][NB][NW];
    __shared__ float wl[NB][NW];

    #pragma unroll
    for (int b = 0; b < NB; ++b)
        qs[b][tid] = queries[(size_t)(n0 + b) * DIM + tid];

    // uniform pos loads issued early so they overlap phase 1
    float cx[NB], cy[NB], ibw[NB], ibh[NB];
    #pragma unroll
    for (int b = 0; b < NB; ++b) {
        cx[b]  = pos[(n0 + b) * 4 + 0];
        cy[b]  = pos[(n0 + b) * 4 + 1];
        ibw[b] = 1.0f / pos[(n0 + b) * 4 + 2];
        ibh[b] = 1.0f / pos[(n0 + b) * 4 + 3];
    }

    __syncthreads();

    // ---- phase 1: weights = q @ Wg + bg, 4-wave x NB-box parallel ----
    {
        const int j  = tid & 63;     // column
        const int g  = tid >> 6;     // wave = d-chunk
        const int db = g * 64;
        const float* wgj = Wg + j;

        float a0[NB], a1[NB], a2[NB], a3[NB];
        #pragma unroll
        for (int b = 0; b < NB; ++b) { a0[b] = a1[b] = a2[b] = a3[b] = 0.f; }

        #pragma unroll 4
        for (int d = 0; d < 64; d += 4) {
            const float wv0 = wgj[(db + d + 0) * NW];
            const float wv1 = wgj[(db + d + 1) * NW];
            const float wv2 = wgj[(db + d + 2) * NW];
            const float wv3 = wgj[(db + d + 3) * NW];
            #pragma unroll
            for (int b = 0; b < NB; ++b) {
                a0[b] = fmaf(qs[b][db + d + 0], wv0, a0[b]);
                a1[b] = fmaf(qs[b][db + d + 1], wv1, a1[b]);
                a2[b] = fmaf(qs[b][db + d + 2], wv2, a2[b]);
                a3[b] = fmaf(qs[b][db + d + 3], wv3, a3[b]);
            }
        }
        #pragma unroll
        for (int b = 0; b < NB; ++b)
            part[g][b][j] = (a0[b] + a1[b]) + (a2[b] + a3[b]);

        if (tid < 4 * NB) {          // column 64: chunk=tid>>1, box=tid&1
            const int gg  = tid >> 1;
            const int b   = tid & (NB - 1);
            const int db4 = gg * 64;
            const float* wg64 = Wg + 64;
            float c0 = 0.f, c1 = 0.f, c2 = 0.f, c3 = 0.f;
            #pragma unroll 4
            for (int d = 0; d < 64; d += 4) {
                c0 = fmaf(qs[b][db4 + d + 0], wg64[(db4 + d + 0) * NW], c0);
                c1 = fmaf(qs[b][db4 + d + 1], wg64[(db4 + d + 1) * NW], c1);
                c2 = fmaf(qs[b][db4 + d + 2], wg64[(db4 + d + 2) * NW], c2);
                c3 = fmaf(qs[b][db4 + d + 3], wg64[(db4 + d + 3) * NW], c3);
            }
            part[gg][b][64] = (c0 + c1) + (c2 + c3);
        }
    }
    __syncthreads();

    if (tid < NB * NW) {             // 130 reduce threads
        const int b  = (tid >= NW) ? 1 : 0;
        const int jj = tid - b * NW;
        wl[b][jj] = bg[jj] + ((part[0][b][jj] + part[1][b][jj]) +
                              (part[2][b][jj] + part[3][b][jj]));
    }
    __syncthreads();

    // ---- phase 2: render NB boxes sequentially ----
    const int xg = tid & 15;   // x-group: owns x0..x0+3
    const int yl = tid >> 4;   // 0..15
    const int x0 = xg * 4;

    #pragma unroll
    for (int b = 0; b < NB; ++b) {
        float w1x[HD], w1y[HD], b1[HD], w2v[HD];
        #pragma unroll
        for (int k = 0; k < HD; ++k) {
            w1x[k] = wl[b][k];
            w1y[k] = wl[b][HD + k];
            b1[k]  = wl[b][2 * HD + k];
            w2v[k] = wl[b][3 * HD + k];
        }
        const float b2 = wl[b][4 * HD];

        float rx[4];
        #pragma unroll
        for (int jx = 0; jx < 4; ++jx)
            rx[jx] = ((x0 + jx + 0.5f) * (1.0f / HW) - cx[b]) * ibw[b];

        float* outn = out + (size_t)(n0 + b) * (HW * HW);

        #pragma unroll
        for (int it = 0; it < 4; ++it) {
            const int y = it * 16 + yl;
            const float ry = ((y + 0.5f) * (1.0f / HW) - cy[b]) * ibh[b];

            float ayb[HD];
            #pragma unroll
            for (int k = 0; k < HD; ++k)
                ayb[k] = fmaf(ry, w1y[k], b1[k]);

            float4 acc = make_float4(b2, b2, b2, b2);
            #pragma unroll
            for (int k = 0; k < HD; ++k) {
                const float t0 = fmaxf(fmaf(rx[0], w1x[k], ayb[k]), 0.0f);
                const float t1 = fmaxf(fmaf(rx[1], w1x[k], ayb[k]), 0.0f);
                const float t2 = fmaxf(fmaf(rx[2], w1x[k], ayb[k]), 0.0f);
                const float t3 = fmaxf(fmaf(rx[3], w1x[k], ayb[k]), 0.0f);
                acc.x = fmaf(t0, w2v[k], acc.x);
                acc.y = fmaf(t1, w2v[k], acc.y);
                acc.z = fmaf(t2, w2v[k], acc.z);
                acc.w = fmaf(t3, w2v[k], acc.w);
            }
            *reinterpret_cast<float4*>(outn + y * HW + x0) = acc;
        }
    }
}

extern "C" void kernel_launch(void* const* d_in, const int* in_sizes, int n_in,
                              void* d_out, int out_size, void* d_ws, size_t ws_size,
                              hipStream_t stream) {
    const float* pos = (const float*)d_in[0];
    const float* q   = (const float*)d_in[1];
    const float* Wg  = (const float*)d_in[2];
    const float* bg  = (const float*)d_in[3];
    float* out = (float*)d_out;

    const int N = in_sizes[0] / 4;   // 8*300 = 2400 boxes
    posmlp_kernel<<<N / NB, 256, 0, stream>>>(pos, q, Wg, bg, out);
}